// Round 2
// baseline (272.357 us; speedup 1.0000x reference)
//
#include <hip/hip_runtime.h>
#include <math.h>

#define B_ 4
#define N_ 2048
#define C_ 64
#define K_ 32
#define BN_ (B_ * N_)  // 8192

// ws float layout
// [0, 8192)        cluster sums (B*K*C), zeroed
// [8192, 8320)     counts (B*K), zeroed
// [8320, 8324)     accum: 0=anchor_sum 1=mask_cnt 2=nll_sum, zeroed
// [8448, 16640)    invn (BN)      (fully overwritten by k_norm_cluster)
// [16640, 24832)   sx (BN)        (fully overwritten by k_zero_prep)
// [24832, 33024)   sy (BN)        (fully overwritten by k_zero_prep)
#define WS_SUMS 0
#define WS_COUNTS 8192
#define WS_ACCUM 8320
#define WS_INVN 8448
#define WS_SX 16640
#define WS_SY 24832

// Zero the accumulator regions AND precompute s = embedding + abs_coords
// (SoA split so k_anchor reads conflict-free float4).
__global__ __launch_bounds__(256) void k_zero_prep(
    const float* __restrict__ emb, const float* __restrict__ absc,
    float* __restrict__ ws) {
  int i = blockIdx.x * 256 + threadIdx.x;  // 33*256 = 8448
  if (i < 8324) ws[i] = 0.0f;
  if (i < BN_) {
    const float2* e2 = (const float2*)emb;
    const float2* a2 = (const float2*)absc;
    float2 ev = e2[i], av = a2[i];
    ws[WS_SX + i] = ev.x + av.x;
    ws[WS_SY + i] = ev.y + av.y;
  }
}

// 32 blocks x 256. Block handles 256 rows of ONE batch (8 blocks/batch).
// Per-row L2 norm (lane = channel), per-block LDS cluster aggregation,
// then 2048 global atomics per block (66K total vs 524K fully-atomic).
__global__ __launch_bounds__(256) void k_norm_cluster(
    const float* __restrict__ contr, const int* __restrict__ labels,
    float* __restrict__ ws) {
  __shared__ float ls[K_ * C_];  // 8 KB
  __shared__ float lc[K_];
  int t = threadIdx.x, lane = t & 63, w = t >> 6;
  for (int i = t; i < K_ * C_; i += 256) ls[i] = 0.0f;
  if (t < K_) lc[t] = 0.0f;
  __syncthreads();
  int rbase = blockIdx.x * 256 + w * 64;
  for (int it = 0; it < 64; ++it) {
    int row = rbase + it;
    float x = contr[row * C_ + lane];
    float ss = x * x;
#pragma unroll
    for (int off = 32; off > 0; off >>= 1) ss += __shfl_xor(ss, off);
    float inv = 1.0f / fmaxf(sqrtf(ss), 1e-12f);
    int lbl = labels[row];
    atomicAdd(&ls[lbl * C_ + lane], x * inv);
    if (lane == 0) {
      atomicAdd(&lc[lbl], 1.0f);
      ws[WS_INVN + row] = inv;
    }
  }
  __syncthreads();
  int b = blockIdx.x >> 3;  // 8 blocks per batch
  for (int i = t; i < K_ * C_; i += 256) atomicAdd(&ws[WS_SUMS + b * K_ * C_ + i], ls[i]);
  if (t < K_) atomicAdd(&ws[WS_COUNTS + b * K_ + t], lc[t]);
}

// 128 blocks x 256 (4 waves). Block = 64 rows (lane = row), wave w = cols
// [w*32, w*32+32). Means staged in LDS (divide fused here — no k_means
// dispatch), row vector held in 16 float4 VGPRs (no per-k LDS traffic),
// means read as wave-uniform b128 broadcasts. Softmax+nll fused in-block.
__global__ __launch_bounds__(256) void k_logits_nll(
    const float* __restrict__ contr, const int* __restrict__ labels,
    float* __restrict__ ws) {
  __shared__ float sm[B_ * K_ * C_];  // 32 KB finalized means
  __shared__ float sred[4 * 64 * 3];  // per-wave (m, s, tl) partials
  int t = threadIdx.x, lane = t & 63, w = t >> 6;
  for (int i = t; i < B_ * K_ * C_; i += 256) {
    float cnt = fmaxf(ws[WS_COUNTS + (i >> 6)], 1.0f);
    sm[i] = ws[WS_SUMS + i] * (1.0f / cnt);
  }
  int row = blockIdx.x * 64 + lane;
  float inv = ws[WS_INVN + row];
  float4 cr[16];
  const float4* crp = (const float4*)(contr + row * C_);
#pragma unroll
  for (int q = 0; q < 16; ++q) {
    float4 v = crp[q];
    cr[q] = make_float4(v.x * inv, v.y * inv, v.z * inv, v.w * inv);
  }
  __syncthreads();
  const float4* sm4 = (const float4*)sm;
  int cbase = w * 32;
  float acc[32];
  for (int j = 0; j < 32; ++j) {
    const float4* mj = sm4 + (cbase + j) * 16;
    float a = 0.0f;
#pragma unroll
    for (int q = 0; q < 16; ++q) {
      float4 m = mj[q];
      a += cr[q].x * m.x + cr[q].y * m.y + cr[q].z * m.z + cr[q].w * m.w;
    }
    acc[j] = a;
  }
  int tgt = labels[row];  // in [0,32): lives in wave 0's col range
  float m = -1e30f, tl = -1e30f;
#pragma unroll
  for (int j = 0; j < 32; ++j) {
    m = fmaxf(m, acc[j]);
    tl = (cbase + j == tgt) ? acc[j] : tl;
  }
  float s = 0.0f;
#pragma unroll
  for (int j = 0; j < 32; ++j) s += __expf(acc[j] - m);
  sred[(w * 64 + lane) * 3 + 0] = m;
  sred[(w * 64 + lane) * 3 + 1] = s;
  sred[(w * 64 + lane) * 3 + 2] = tl;
  __syncthreads();
  if (w == 0) {
    float mm = -1e30f, stot = 0.0f, tt = -1e30f;
#pragma unroll
    for (int g = 0; g < 4; ++g) mm = fmaxf(mm, sred[(g * 64 + lane) * 3 + 0]);
#pragma unroll
    for (int g = 0; g < 4; ++g) {
      stot += sred[(g * 64 + lane) * 3 + 1] * __expf(sred[(g * 64 + lane) * 3 + 0] - mm);
      tt = fmaxf(tt, sred[(g * 64 + lane) * 3 + 2]);
    }
    float nll = (mm + logf(stot)) - tt;
#pragma unroll
    for (int off = 32; off > 0; off >>= 1) nll += __shfl_xor(nll, off);
    if (lane == 0) atomicAdd(&ws[WS_ACCUM + 2], nll);
  }
}

__device__ __forceinline__ void pair4(float sx, float sy, float4 xs, float4 ys,
                                      int4 m, float& acc, float& cnt) {
  float dx, dy, d2, v;
  dx = sx - xs.x; dy = sy - ys.x; d2 = dx * dx + dy * dy;
  v = 1.0f - __expf(d2 * -0.1f);
  if (m.x == 1) { acc += v; cnt += 1.0f; }
  dx = sx - xs.y; dy = sy - ys.y; d2 = dx * dx + dy * dy;
  v = 1.0f - __expf(d2 * -0.1f);
  if (m.y == 1) { acc += v; cnt += 1.0f; }
  dx = sx - xs.z; dy = sy - ys.z; d2 = dx * dx + dy * dy;
  v = 1.0f - __expf(d2 * -0.1f);
  if (m.z == 1) { acc += v; cnt += 1.0f; }
  dx = sx - xs.w; dy = sy - ys.w; d2 = dx * dx + dy * dy;
  v = 1.0f - __expf(d2 * -0.1f);
  if (m.w == 1) { acc += v; cnt += 1.0f; }
}

// 4096 blocks x 256. Block = 2 rows; thread = 2 chunks/row -> 4 independent
// int4 mask loads + 4 float4 s-loads issued before any compute (MLP). No LDS
// staging: s-values come from ws (16 KB/batch, L1/L2-hot across blocks).
__global__ __launch_bounds__(256) void k_anchor(
    const int* __restrict__ mask, float* ws) {
  __shared__ float red[8];
  int t = threadIdx.x;
  int row0 = blockIdx.x * 2;
  int b = row0 >> 11;
  float ax0 = ws[WS_SX + row0], ay0 = ws[WS_SY + row0];
  float ax1 = ws[WS_SX + row0 + 1], ay1 = ws[WS_SY + row0 + 1];
  const float4* bx = (const float4*)(ws + WS_SX + b * N_);
  const float4* by = (const float4*)(ws + WS_SY + b * N_);
  const int4* m0 = (const int4*)(mask + (size_t)row0 * N_);
  const int4* m1 = (const int4*)(mask + (size_t)(row0 + 1) * N_);
  int4 A0 = m0[t], A1 = m0[t + 256];
  int4 B0 = m1[t], B1 = m1[t + 256];
  float4 X0 = bx[t], Y0 = by[t];
  float4 X1 = bx[t + 256], Y1 = by[t + 256];
  float acc = 0.0f, cnt = 0.0f;
  pair4(ax0, ay0, X0, Y0, A0, acc, cnt);
  pair4(ax0, ay0, X1, Y1, A1, acc, cnt);
  pair4(ax1, ay1, X0, Y0, B0, acc, cnt);
  pair4(ax1, ay1, X1, Y1, B1, acc, cnt);
#pragma unroll
  for (int off = 32; off > 0; off >>= 1) {
    acc += __shfl_xor(acc, off);
    cnt += __shfl_xor(cnt, off);
  }
  int w = t >> 6;
  if ((t & 63) == 0) { red[w * 2] = acc; red[w * 2 + 1] = cnt; }
  __syncthreads();
  if (t == 0) {
    float a = red[0] + red[2] + red[4] + red[6];
    float c = red[1] + red[3] + red[5] + red[7];
    atomicAdd(&ws[WS_ACCUM + 0], a);
    atomicAdd(&ws[WS_ACCUM + 1], c);
  }
}

__global__ void k_final(const float* __restrict__ ws, float* __restrict__ out) {
  out[0] = ws[WS_ACCUM + 0] / ws[WS_ACCUM + 1] +
           10.0f * ws[WS_ACCUM + 2] * (1.0f / (float)BN_);
}

extern "C" void kernel_launch(void* const* d_in, const int* in_sizes, int n_in,
                              void* d_out, int out_size, void* d_ws, size_t ws_size,
                              hipStream_t stream) {
  const float* emb    = (const float*)d_in[0];
  const float* contr  = (const float*)d_in[1];
  const float* absc   = (const float*)d_in[2];
  const int*   mask   = (const int*)d_in[3];
  const int*   labels = (const int*)d_in[4];
  float* ws  = (float*)d_ws;
  float* out = (float*)d_out;

  k_zero_prep<<<33, 256, 0, stream>>>(emb, absc, ws);
  k_norm_cluster<<<32, 256, 0, stream>>>(contr, labels, ws);
  k_logits_nll<<<BN_ / 64, 256, 0, stream>>>(contr, labels, ws);
  k_anchor<<<BN_ / 2, 256, 0, stream>>>(mask, ws);
  k_final<<<1, 1, 0, stream>>>(ws, out);
}